// Round 17
// baseline (50.628 us; speedup 1.0000x reference)
//
#include <hip/hip_runtime.h>

namespace {

constexpr int NB = 4, ND = 128, NH = 192, NW = 192;
constexpr int PLI = NH * NW;
constexpr int CD = 16;    // output planes per block; 128/16 = 8 exact

__global__ __launch_bounds__(128, 2)
void edge_loss3d(const float* __restrict__ pred,
                 const float* __restrict__ targ,
                 float* __restrict__ out)
{
    const int lane = threadIdx.x & 63;
    const int wid  = threadIdx.x >> 6;     // 0: pred-wave, 1: targ-wave
    const int d0   = blockIdx.x * CD;
    const int h0   = blockIdx.y * 4;       // block's 4 output rows h0..h0+3
    const int b    = blockIdx.z;

    __shared__ float eL[2][4][192];        // [parity][row][w] edge-mag exchange
    __shared__ float wsum[2];

    // each wave owns ONE tensor for the whole strip
    const float* sb = (wid ? targ : pred) + (size_t)b * ND * PLI + 3 * lane;

    // input rows h0-1 .. h0+4 (6 rows), clamped; masks for the 2 edge rows
    const int r0 = (h0 - 1 < 0 ? 0 : h0 - 1) * NW;
    const int r1 = h0 * NW;
    const int r2 = (h0 + 1) * NW;
    const int r3 = (h0 + 2) * NW;
    const int r4 = (h0 + 3) * NW;
    const int r5 = (h0 + 4 > NH - 1 ? NH - 1 : h0 + 4) * NW;
    const float m0 = (h0 - 1 >= 0) ? 1.f : 0.f;
    const float m5 = (h0 + 4 < NH) ? 1.f : 0.f;

    // rolling UNSCALED output accumulators: a[slot][comp 0=gx 1=gy 2=gz][row][w]
    // slot roles rotate (F=finish, M=mid, I=init) — all literal indices.
    float a[3][3][4][3];
    float acc = 0.f;

// one output row J: u/v h-conv from 3 named input rows, w-halo via shuffles,
// then w-convs (st,ts,ss) feed slots I (init), M (+2x), F (finish -> e).
#define ROWC(F, M, I, J, A0, A1, A2, B0, B1, B2, C0, C1, C2, PM, DOEMIT) do { \
    const float u0_ = fmaf(2.f, B0, (A0) + (C0)) * (PM);                      \
    const float u1_ = fmaf(2.f, B1, (A1) + (C1)) * (PM);                      \
    const float u2_ = fmaf(2.f, B2, (A2) + (C2)) * (PM);                      \
    const float v0_ = ((C0) - (A0)) * (PM);                                   \
    const float v1_ = ((C1) - (A1)) * (PM);                                   \
    const float v2_ = ((C2) - (A2)) * (PM);                                   \
    float um_ = __shfl_up(u2_, 1, 64),  up_ = __shfl_down(u0_, 1, 64);        \
    float vm_ = __shfl_up(v2_, 1, 64),  vp_ = __shfl_down(v0_, 1, 64);        \
    if (lane == 0)  { um_ = 0.f; vm_ = 0.f; }                                 \
    if (lane == 63) { up_ = 0.f; vp_ = 0.f; }                                 \
    const float ss0_ = fmaf(2.f, u0_, um_ + u1_);                             \
    const float ss1_ = fmaf(2.f, u1_, u0_ + u2_);                             \
    const float ss2_ = fmaf(2.f, u2_, u1_ + up_);                             \
    const float ts0_ = fmaf(2.f, v0_, vm_ + v1_);                             \
    const float ts1_ = fmaf(2.f, v1_, v0_ + v2_);                             \
    const float ts2_ = fmaf(2.f, v2_, v1_ + vp_);                             \
    const float st0_ = u1_ - um_, st1_ = u2_ - u0_, st2_ = up_ - u1_;         \
    if (DOEMIT) {                                                             \
        const float gx0_ = a[F][0][J][0] + st0_;                              \
        const float gx1_ = a[F][0][J][1] + st1_;                              \
        const float gx2_ = a[F][0][J][2] + st2_;                              \
        const float gy0_ = a[F][1][J][0] + ts0_;                              \
        const float gy1_ = a[F][1][J][1] + ts1_;                              \
        const float gy2_ = a[F][1][J][2] + ts2_;                              \
        const float gz0_ = ss0_ - a[F][2][J][0];                              \
        const float gz1_ = ss1_ - a[F][2][J][1];                              \
        const float gz2_ = ss2_ - a[F][2][J][2];                              \
        const float d0_ = fmaf(gz0_, gz0_, fmaf(gy0_, gy0_, fmaf(gx0_, gx0_, 2.56e-6f))); \
        const float d1_ = fmaf(gz1_, gz1_, fmaf(gy1_, gy1_, fmaf(gx1_, gx1_, 2.56e-6f))); \
        const float d2_ = fmaf(gz2_, gz2_, fmaf(gy2_, gy2_, fmaf(gx2_, gx2_, 2.56e-6f))); \
        asm("v_sqrt_f32 %0, %1" : "=v"(eo[J][0]) : "v"(d0_));                 \
        asm("v_sqrt_f32 %0, %1" : "=v"(eo[J][1]) : "v"(d1_));                 \
        asm("v_sqrt_f32 %0, %1" : "=v"(eo[J][2]) : "v"(d2_));                 \
    }                                                                         \
    a[M][0][J][0] = fmaf(2.f, st0_, a[M][0][J][0]);                           \
    a[M][0][J][1] = fmaf(2.f, st1_, a[M][0][J][1]);                           \
    a[M][0][J][2] = fmaf(2.f, st2_, a[M][0][J][2]);                           \
    a[M][1][J][0] = fmaf(2.f, ts0_, a[M][1][J][0]);                           \
    a[M][1][J][1] = fmaf(2.f, ts1_, a[M][1][J][1]);                           \
    a[M][1][J][2] = fmaf(2.f, ts2_, a[M][1][J][2]);                           \
    a[I][0][J][0] = st0_; a[I][0][J][1] = st1_; a[I][0][J][2] = st2_;         \
    a[I][1][J][0] = ts0_; a[I][1][J][1] = ts1_; a[I][1][J][2] = ts2_;         \
    a[I][2][J][0] = ss0_; a[I][2][J][1] = ss1_; a[I][2][J][2] = ss2_;         \
} while (0)

// one phase: load 6 rows of own tensor at plane offset O_, run 4 rows,
// exchange e through LDS (raw barrier, lgkmcnt only — globals stay in flight)
#define PHASE_BODY(F, M, I, PAR, O_, PM, DOEMIT) do {                         \
    float eo[4][3];                                                           \
    float x00 = sb[(O_) + r0], x01 = sb[(O_) + r0 + 1], x02 = sb[(O_) + r0 + 2]; \
    float x10 = sb[(O_) + r1], x11 = sb[(O_) + r1 + 1], x12 = sb[(O_) + r1 + 2]; \
    float x20 = sb[(O_) + r2], x21 = sb[(O_) + r2 + 1], x22 = sb[(O_) + r2 + 2]; \
    float x30 = sb[(O_) + r3], x31 = sb[(O_) + r3 + 1], x32 = sb[(O_) + r3 + 2]; \
    float x40 = sb[(O_) + r4], x41 = sb[(O_) + r4 + 1], x42 = sb[(O_) + r4 + 2]; \
    float x50 = sb[(O_) + r5], x51 = sb[(O_) + r5 + 1], x52 = sb[(O_) + r5 + 2]; \
    x00 *= m0; x01 *= m0; x02 *= m0;                                          \
    x50 *= m5; x51 *= m5; x52 *= m5;                                          \
    ROWC(F, M, I, 0, x00, x01, x02, x10, x11, x12, x20, x21, x22, PM, DOEMIT);\
    ROWC(F, M, I, 1, x10, x11, x12, x20, x21, x22, x30, x31, x32, PM, DOEMIT);\
    ROWC(F, M, I, 2, x20, x21, x22, x30, x31, x32, x40, x41, x42, PM, DOEMIT);\
    ROWC(F, M, I, 3, x30, x31, x32, x40, x41, x42, x50, x51, x52, PM, DOEMIT);\
    if (DOEMIT) {                                                             \
        if (wid == 0) {                                                       \
            eL[PAR][0][3*lane+0] = eo[0][0]; eL[PAR][0][3*lane+1] = eo[0][1]; eL[PAR][0][3*lane+2] = eo[0][2]; \
            eL[PAR][1][3*lane+0] = eo[1][0]; eL[PAR][1][3*lane+1] = eo[1][1]; eL[PAR][1][3*lane+2] = eo[1][2]; \
            eL[PAR][2][3*lane+0] = eo[2][0]; eL[PAR][2][3*lane+1] = eo[2][1]; eL[PAR][2][3*lane+2] = eo[2][2]; \
            eL[PAR][3][3*lane+0] = eo[3][0]; eL[PAR][3][3*lane+1] = eo[3][1]; eL[PAR][3][3*lane+2] = eo[3][2]; \
        }                                                                     \
        asm volatile("s_waitcnt lgkmcnt(0)" ::: "memory");                    \
        __builtin_amdgcn_s_barrier();                                         \
        if (wid == 1) {                                                       \
            acc += fabsf(eo[0][0] - eL[PAR][0][3*lane+0]);                    \
            acc += fabsf(eo[0][1] - eL[PAR][0][3*lane+1]);                    \
            acc += fabsf(eo[0][2] - eL[PAR][0][3*lane+2]);                    \
            acc += fabsf(eo[1][0] - eL[PAR][1][3*lane+0]);                    \
            acc += fabsf(eo[1][1] - eL[PAR][1][3*lane+1]);                    \
            acc += fabsf(eo[1][2] - eL[PAR][1][3*lane+2]);                    \
            acc += fabsf(eo[2][0] - eL[PAR][2][3*lane+0]);                    \
            acc += fabsf(eo[2][1] - eL[PAR][2][3*lane+1]);                    \
            acc += fabsf(eo[2][2] - eL[PAR][2][3*lane+2]);                    \
            acc += fabsf(eo[3][0] - eL[PAR][3][3*lane+0]);                    \
            acc += fabsf(eo[3][1] - eL[PAR][3][3*lane+1]);                    \
            acc += fabsf(eo[3][2] - eL[PAR][3][3*lane+2]);                    \
        }                                                                     \
    }                                                                         \
} while (0)

// in-range plane
#define PH(F, M, I, PAR, P, DOEMIT) do {                                      \
    const int o_ = (P) * PLI;                                                 \
    PHASE_BODY(F, M, I, PAR, o_, 1.f, DOEMIT);                                \
} while (0)

// possibly-OOB plane (first/last phase at grid d-edges)
#define PHM(F, M, I, PAR, P, DOEMIT) do {                                     \
    const int pc_ = (P) < 0 ? 0 : ((P) > ND - 1 ? ND - 1 : (P));              \
    const float pm_ = ((P) >= 0 && (P) < ND) ? 1.f : 0.f;                     \
    const int o_ = pc_ * PLI;                                                 \
    PHASE_BODY(F, M, I, PAR, o_, pm_, DOEMIT);                                \
} while (0)

    // 18 phases k=0..17: input plane p = d0-1+k; slots F=k%3, M=(k+1)%3,
    // I=(k+2)%3; e-parity k%2; EMIT (out plane p-1) from k>=2.
    PHM(0, 1, 2, 0, d0 - 1, 0);               // k=0 (OOB for first block)
    PH (1, 2, 0, 1, d0,     0);               // k=1
    for (int gg = 0; gg < 2; ++gg) {          // k=2..13
        const int p = d0 + 1 + 6 * gg;
        PH(2, 0, 1, 0, p,     1);
        PH(0, 1, 2, 1, p + 1, 1);
        PH(1, 2, 0, 0, p + 2, 1);
        PH(2, 0, 1, 1, p + 3, 1);
        PH(0, 1, 2, 0, p + 4, 1);
        PH(1, 2, 0, 1, p + 5, 1);
    }
    PH (2, 0, 1, 0, d0 + 13, 1);              // k=14
    PH (0, 1, 2, 1, d0 + 14, 1);              // k=15
    PH (1, 2, 0, 0, d0 + 15, 1);              // k=16
    PHM(2, 0, 1, 1, d0 + 16, 1);              // k=17 (OOB for last block)

#undef ROWC
#undef PHASE_BODY
#undef PH
#undef PHM

    // wave reduce -> block reduce -> one atomic per block
    #pragma unroll
    for (int off = 32; off > 0; off >>= 1)
        acc += __shfl_down(acc, off, 64);
    if (lane == 0) wsum[wid] = acc;
    __syncthreads();
    if (threadIdx.x == 0) {
        // fold the exact 1/16 kernel scale and the mean into one constant
        const float invN = 1.f / (16.f * (float)((long long)NB * ND * NH * NW));
        atomicAdd(out, (wsum[0] + wsum[1]) * invN);
    }
}

} // namespace

extern "C" void kernel_launch(void* const* d_in, const int* in_sizes, int n_in,
                              void* d_out, int out_size, void* d_ws, size_t ws_size,
                              hipStream_t stream) {
    const float* pred = (const float*)d_in[0];
    const float* targ = (const float*)d_in[1];
    float* out = (float*)d_out;
    (void)in_sizes; (void)n_in; (void)out_size; (void)d_ws; (void)ws_size;

    hipMemsetAsync(out, 0, sizeof(float), stream);

    dim3 grid(ND / CD, NH / 4, NB);   // (8, 48, 4) = 1536 blocks x 2 waves
    dim3 block(128);
    edge_loss3d<<<grid, block, 0, stream>>>(pred, targ, out);
}

// Round 18
// 43.922 us; speedup vs baseline: 1.1527x; 1.1527x over previous
//
#include <hip/hip_runtime.h>

namespace {

struct f3 { float x, y, z; };   // size 12, align 4 -> global_load_dwordx3

constexpr int NB = 4, ND = 128, NH = 192, NW = 192;
constexpr int PLI = NH * NW;
constexpr int CD = 16;    // output planes per block; 128/16 = 8 exact

__global__ __launch_bounds__(256, 2)
void edge_loss3d(const float* __restrict__ pred,
                 const float* __restrict__ targ,
                 float* __restrict__ out)
{
    const int lane = threadIdx.x & 63;
    const int wid  = threadIdx.x >> 6;
    const int d0   = blockIdx.x * CD;
    const int h    = blockIdx.y * 8 + 2 * wid; // wave's output rows h, h+1
    const int b    = blockIdx.z;

    // per-lane bases: 3 w-elements per lane, all 64 lanes active
    const float* sb0 = pred + (size_t)b * ND * PLI + 3 * lane;
    const float* sb1 = targ + (size_t)b * ND * PLI + 3 * lane;

    // 4 input rows h-1..h+2 (clamped) + wave-uniform edge masks
    const int ro0 = (h - 1 < 0 ? 0 : h - 1) * NW;
    const int ro1 = h * NW;
    const int ro2 = (h + 1) * NW;                      // always valid
    const int ro3 = (h + 2 > NH - 1 ? NH - 1 : h + 2) * NW;
    const float m0 = (h - 1 >= 0) ? 1.f : 0.f;
    const float m3 = (h + 2 < NH) ? 1.f : 0.f;

    // rolling UNSCALED conv state: q[tensor][slot][kind][row][w] = 108 floats
    float q[2][3][3][2][3];
    float acc = 0.f;

// write one output row's (ss,ts,st) from named u/v + halos (literal indices)
#define QROW(T, SP, R, U0, U1, U2, UM, UP, V0, V1, V2, VM, VP) do {           \
    q[T][SP][0][R][0] = fmaf(2.f, U0, UM + U1);                               \
    q[T][SP][0][R][1] = fmaf(2.f, U1, U0 + U2);                               \
    q[T][SP][0][R][2] = fmaf(2.f, U2, U1 + UP);                               \
    q[T][SP][1][R][0] = fmaf(2.f, V0, VM + V1);                               \
    q[T][SP][1][R][1] = fmaf(2.f, V1, V0 + V2);                               \
    q[T][SP][1][R][2] = fmaf(2.f, V2, V1 + VP);                               \
    q[T][SP][2][R][0] = U1 - UM;                                              \
    q[T][SP][2][R][1] = U2 - U0;                                              \
    q[T][SP][2][R][2] = UP - U1;                                              \
} while (0)

// one tensor, one plane, into slot SP. PM = plane mask (1.f when in range).
// 4 x dwordx3 loads, h-conv for 2 output rows, w-halo via 8 shuffles.
#define TPASS(T, SP, OFS, PM) do {                                            \
    const float* s_ = (T) ? sb1 : sb0;                                        \
    const f3 A_ = *(const f3*)(s_ + (OFS) + ro0);                             \
    const f3 B_ = *(const f3*)(s_ + (OFS) + ro1);                             \
    const f3 C_ = *(const f3*)(s_ + (OFS) + ro2);                             \
    const f3 D_ = *(const f3*)(s_ + (OFS) + ro3);                             \
    const float a0_ = A_.x * m0, a1_ = A_.y * m0, a2_ = A_.z * m0;            \
    const float b0_ = B_.x, b1_ = B_.y, b2_ = B_.z;                           \
    const float c0_ = C_.x, c1_ = C_.y, c2_ = C_.z;                           \
    const float d0_ = D_.x * m3, d1_ = D_.y * m3, d2_ = D_.z * m3;            \
    float uA0_ = fmaf(2.f, b0_, a0_ + c0_) * (PM);                            \
    float uA1_ = fmaf(2.f, b1_, a1_ + c1_) * (PM);                            \
    float uA2_ = fmaf(2.f, b2_, a2_ + c2_) * (PM);                            \
    float uB0_ = fmaf(2.f, c0_, b0_ + d0_) * (PM);                            \
    float uB1_ = fmaf(2.f, c1_, b1_ + d1_) * (PM);                            \
    float uB2_ = fmaf(2.f, c2_, b2_ + d2_) * (PM);                            \
    float vA0_ = (c0_ - a0_) * (PM), vA1_ = (c1_ - a1_) * (PM), vA2_ = (c2_ - a2_) * (PM); \
    float vB0_ = (d0_ - b0_) * (PM), vB1_ = (d1_ - b1_) * (PM), vB2_ = (d2_ - b2_) * (PM); \
    float uAm_ = __shfl_up(uA2_, 1, 64), uAp_ = __shfl_down(uA0_, 1, 64);     \
    float uBm_ = __shfl_up(uB2_, 1, 64), uBp_ = __shfl_down(uB0_, 1, 64);     \
    float vAm_ = __shfl_up(vA2_, 1, 64), vAp_ = __shfl_down(vA0_, 1, 64);     \
    float vBm_ = __shfl_up(vB2_, 1, 64), vBp_ = __shfl_down(vB0_, 1, 64);     \
    if (lane == 0)  { uAm_ = 0.f; uBm_ = 0.f; vAm_ = 0.f; vBm_ = 0.f; }       \
    if (lane == 63) { uAp_ = 0.f; uBp_ = 0.f; vAp_ = 0.f; vBp_ = 0.f; }       \
    QROW(T, SP, 0, uA0_, uA1_, uA2_, uAm_, uAp_, vA0_, vA1_, vA2_, vAm_, vAp_); \
    QROW(T, SP, 1, uB0_, uB1_, uB2_, uBm_, uBp_, vB0_, vB1_, vB2_, vBm_, vBp_); \
} while (0)

// both tensors, plane P guaranteed in range
#define TPP(SP, P) do {                                                       \
    const int o_ = (P) * PLI;                                                 \
    TPASS(0, SP, o_, 1.f); TPASS(1, SP, o_, 1.f);                             \
} while (0)

// both tensors, plane P may be out of range (blocks at d-edges)
#define TPM(SP, P) do {                                                       \
    const int pc_ = (P) < 0 ? 0 : ((P) > ND - 1 ? ND - 1 : (P));              \
    const float pm_ = ((P) >= 0 && (P) < ND) ? 1.f : 0.f;                     \
    const int o_ = pc_ * PLI;                                                 \
    TPASS(0, SP, o_, pm_); TPASS(1, SP, o_, pm_);                             \
} while (0)

// unscaled magnitude: conv scales exactly 16x; eps_u = 256e-8; v_sqrt 1 inst
#define EDGE1(T, R, J, SM, SC, SP, E) do {                                    \
    const float gx_ = fmaf(2.f, q[T][SC][2][R][J], q[T][SM][2][R][J] + q[T][SP][2][R][J]); \
    const float gy_ = fmaf(2.f, q[T][SC][1][R][J], q[T][SM][1][R][J] + q[T][SP][1][R][J]); \
    const float gz_ = q[T][SP][0][R][J] - q[T][SM][0][R][J];                  \
    const float d_ = fmaf(gz_, gz_, fmaf(gy_, gy_, fmaf(gx_, gx_, 2.56e-6f)));\
    asm("v_sqrt_f32 %0, %1" : "=v"(E) : "v"(d_));                             \
} while (0)

#define EMIT1(R, J, SM, SC, SP) do {                                          \
    float e0_, e1_;                                                           \
    EDGE1(0, R, J, SM, SC, SP, e0_);                                          \
    EDGE1(1, R, J, SM, SC, SP, e1_);                                          \
    acc += fabsf(e0_ - e1_);                                                  \
} while (0)

#define EMIT(SM, SC, SP) do {                                                 \
    EMIT1(0, 0, SM, SC, SP); EMIT1(0, 1, SM, SC, SP); EMIT1(0, 2, SM, SC, SP);\
    EMIT1(1, 0, SM, SC, SP); EMIT1(1, 1, SM, SC, SP); EMIT1(1, 2, SM, SC, SP);\
} while (0)

    // 18 phases k=0..17: plane d0-1+k -> slot k%3; EMIT from k>=2. No barriers.
    TPM(0, d0 - 1);                           // k=0 (OOB only for first block)
    TPP(1, d0);                               // k=1
    for (int gg = 0; gg < 5; ++gg) {          // k=2..16
        const int p = d0 + 1 + 3 * gg;
        TPP(2, p);     EMIT(0, 1, 2);
        TPP(0, p + 1); EMIT(1, 2, 0);
        TPP(1, p + 2); EMIT(2, 0, 1);
    }
    TPM(2, d0 + 16); EMIT(0, 1, 2);           // k=17 (OOB only for last block)

#undef QROW
#undef TPASS
#undef TPP
#undef TPM
#undef EDGE1
#undef EMIT1
#undef EMIT

    // wave reduce -> block reduce -> one atomic per block
    #pragma unroll
    for (int off = 32; off > 0; off >>= 1)
        acc += __shfl_down(acc, off, 64);
    __shared__ float wsum[4];
    if (lane == 0) wsum[wid] = acc;
    __syncthreads();
    if (threadIdx.x == 0) {
        // fold the exact 1/16 kernel scale and the mean into one constant
        const float invN = 1.f / (16.f * (float)((long long)NB * ND * NH * NW));
        atomicAdd(out, (wsum[0] + wsum[1] + wsum[2] + wsum[3]) * invN);
    }
}

} // namespace

extern "C" void kernel_launch(void* const* d_in, const int* in_sizes, int n_in,
                              void* d_out, int out_size, void* d_ws, size_t ws_size,
                              hipStream_t stream) {
    const float* pred = (const float*)d_in[0];
    const float* targ = (const float*)d_in[1];
    float* out = (float*)d_out;
    (void)in_sizes; (void)n_in; (void)out_size; (void)d_ws; (void)ws_size;

    hipMemsetAsync(out, 0, sizeof(float), stream);

    dim3 grid(ND / CD, NH / 8, NB);   // (8, 24, 4) = 768 blocks, 12 waves/CU
    dim3 block(256);
    edge_loss3d<<<grid, block, 0, stream>>>(pred, targ, out);
}